// Round 2
// baseline (36.029 us; speedup 1.0000x reference)
//
#include <hip/hip_runtime.h>

#define BATCH 256
#define SEQ   512
#define DIM   64
#define VOC   100
#define NTHREADS 512
#define ENC_PITCH 68   // floats (fused fallback only)

#define K2_BLOCKS  2048
#define K2_THREADS 256

// ---------------- K1: per-row histogram + MLP -> enc table in global ws ----
__global__ __launch_bounds__(NTHREADS)
void enc_kernel(const int* __restrict__ src_ids,
                const int* __restrict__ dst_ids,
                const float* __restrict__ W1,
                const float* __restrict__ b1,
                const float* __restrict__ W2,
                const float* __restrict__ b2,
                float4* __restrict__ enc_ws)   // [BATCH][VOC][16] float4
{
    __shared__ __align__(16) float sW2[DIM][DIM];
    __shared__ __align__(16) float sW1[2][DIM];
    __shared__ __align__(16) float sb1[DIM];
    __shared__ __align__(16) float sb2[DIM];
    __shared__ int hist_s[104];
    __shared__ int hist_d[104];

    const int t   = threadIdx.x;
    const int row = blockIdx.x;

    if (t < 104) { hist_s[t] = 0; hist_d[t] = 0; }
    {
        const float4* W2v  = (const float4*)W2;
        float4*       sW2v = (float4*)&sW2[0][0];
        sW2v[t]       = W2v[t];
        sW2v[t + 512] = W2v[t + 512];
        if (t < 32)      ((float4*)&sW1[0][0])[t] = ((const float4*)W1)[t];
        else if (t < 48) ((float4*)sb1)[t - 32]   = ((const float4*)b1)[t - 32];
        else if (t < 64) ((float4*)sb2)[t - 48]   = ((const float4*)b2)[t - 48];
    }
    __syncthreads();

    {
        int a = src_ids[row * SEQ + t];
        int b = dst_ids[row * SEQ + t];
        atomicAdd(&hist_s[a], 1);
        atomicAdd(&hist_d[b], 1);
    }
    __syncthreads();

    if (t < 400) {
        const int tv = t >> 4;        // 0..24
        const int to = t & 15;        // 0..15
        const int vbase = tv * 4;
        const int obase = to * 4;

        float av[4], bv[4];
        #pragma unroll
        for (int r = 0; r < 4; ++r) {
            int v = vbase + r;
            av[r] = (v == 0) ? 0.f : (float)hist_s[v];
            bv[r] = (v == 0) ? 0.f : (float)hist_d[v];
        }

        float acc[4][4];
        #pragma unroll
        for (int r = 0; r < 4; ++r)
            #pragma unroll
            for (int c = 0; c < 4; ++c)
                acc[r][c] = sb2[obase + c];

        #pragma unroll 8
        for (int d = 0; d < DIM; ++d) {
            float w10 = sW1[0][d];
            float w11 = sW1[1][d];
            float bb  = sb1[d];
            float4 w2 = *(const float4*)&sW2[d][obase];
            #pragma unroll
            for (int r = 0; r < 4; ++r) {
                float h = fmaxf(0.f, fmaf(av[r], w10, fmaf(bv[r], w11, bb)));
                acc[r][0] = fmaf(h, w2.x, acc[r][0]);
                acc[r][1] = fmaf(h, w2.y, acc[r][1]);
                acc[r][2] = fmaf(h, w2.z, acc[r][2]);
                acc[r][3] = fmaf(h, w2.w, acc[r][3]);
            }
        }

        #pragma unroll
        for (int r = 0; r < 4; ++r) {
            float4 res = make_float4(acc[r][0], acc[r][1], acc[r][2], acc[r][3]);
            enc_ws[((size_t)(row * VOC + vbase + r) << 4) + to] = res;
        }
    }
}

// ---------------- K2: pure gather, full occupancy, coalesced stores --------
__global__ __launch_bounds__(K2_THREADS)
void gather_kernel(const int* __restrict__ src_ids,
                   const int* __restrict__ dst_ids,
                   const float4* __restrict__ enc_ws,
                   float4* __restrict__ out4)
{
    const int tot = BATCH * SEQ * (DIM / 4);          // 2,097,152 float4 per tensor
    int u = blockIdx.x * K2_THREADS + threadIdx.x;
    const int stride = K2_BLOCKS * K2_THREADS;        // 524,288
    #pragma unroll
    for (int k = 0; k < 4; ++k, u += stride) {
        int row = u >> 13;            // per row: 512*16 = 8192 float4
        int j   = (u >> 4) & (SEQ - 1);
        int q   = u & 15;
        int idx = row * SEQ + j;
        int vs  = src_ids[idx];
        int vd  = dst_ids[idx];
        float4 r1 = enc_ws[((size_t)(row * VOC + vs) << 4) | q];
        float4 r2 = enc_ws[((size_t)(row * VOC + vd) << 4) | q];
        out4[u]       = r1;
        out4[tot + u] = r2;
    }
}

// ---------------- fused fallback (round-1 kernel) if ws too small ----------
__global__ __launch_bounds__(NTHREADS)
void ncoe_fused_kernel(const int* __restrict__ src_ids,
                       const int* __restrict__ dst_ids,
                       const float* __restrict__ W1,
                       const float* __restrict__ b1,
                       const float* __restrict__ W2,
                       const float* __restrict__ b2,
                       float* __restrict__ out)
{
    __shared__ __align__(16) float sW2[DIM][DIM];
    __shared__ __align__(16) float sW1[2][DIM];
    __shared__ __align__(16) float sb1[DIM];
    __shared__ __align__(16) float sb2[DIM];
    __shared__ __align__(16) float enc[VOC][ENC_PITCH];
    __shared__ int hist_s[104];
    __shared__ int hist_d[104];

    const int t   = threadIdx.x;
    const int row = blockIdx.x;

    if (t < 104) { hist_s[t] = 0; hist_d[t] = 0; }
    {
        const float4* W2v  = (const float4*)W2;
        float4*       sW2v = (float4*)&sW2[0][0];
        sW2v[t]       = W2v[t];
        sW2v[t + 512] = W2v[t + 512];
        if (t < 32)      ((float4*)&sW1[0][0])[t] = ((const float4*)W1)[t];
        else if (t < 48) ((float4*)sb1)[t - 32]   = ((const float4*)b1)[t - 32];
        else if (t < 64) ((float4*)sb2)[t - 48]   = ((const float4*)b2)[t - 48];
    }
    __syncthreads();

    {
        int a = src_ids[row * SEQ + t];
        int b = dst_ids[row * SEQ + t];
        atomicAdd(&hist_s[a], 1);
        atomicAdd(&hist_d[b], 1);
    }
    __syncthreads();

    if (t < 400) {
        const int tv = t >> 4;
        const int to = t & 15;
        const int vbase = tv * 4;
        const int obase = to * 4;

        float av[4], bv[4];
        #pragma unroll
        for (int r = 0; r < 4; ++r) {
            int v = vbase + r;
            av[r] = (v == 0) ? 0.f : (float)hist_s[v];
            bv[r] = (v == 0) ? 0.f : (float)hist_d[v];
        }

        float acc[4][4];
        #pragma unroll
        for (int r = 0; r < 4; ++r)
            #pragma unroll
            for (int c = 0; c < 4; ++c)
                acc[r][c] = sb2[obase + c];

        #pragma unroll 8
        for (int d = 0; d < DIM; ++d) {
            float w10 = sW1[0][d];
            float w11 = sW1[1][d];
            float bb  = sb1[d];
            float4 w2 = *(const float4*)&sW2[d][obase];
            #pragma unroll
            for (int r = 0; r < 4; ++r) {
                float h = fmaxf(0.f, fmaf(av[r], w10, fmaf(bv[r], w11, bb)));
                acc[r][0] = fmaf(h, w2.x, acc[r][0]);
                acc[r][1] = fmaf(h, w2.y, acc[r][1]);
                acc[r][2] = fmaf(h, w2.z, acc[r][2]);
                acc[r][3] = fmaf(h, w2.w, acc[r][3]);
            }
        }

        #pragma unroll
        for (int r = 0; r < 4; ++r) {
            float4 res = make_float4(acc[r][0], acc[r][1], acc[r][2], acc[r][3]);
            *(float4*)&enc[vbase + r][obase] = res;
        }
    }
    __syncthreads();

    float4* out4 = (float4*)out;
    const size_t rowOff = (size_t)row * (SEQ * DIM / 4);
    const size_t dstOff = (size_t)BATCH * (size_t)(SEQ * DIM / 4);
    #pragma unroll
    for (int k = 0; k < (SEQ * DIM / 4) / NTHREADS; ++k) {
        int it = t + k * NTHREADS;
        int j  = it >> 4;
        int q  = (it & 15) << 2;
        int vs = src_ids[row * SEQ + j];
        int vd = dst_ids[row * SEQ + j];
        float4 r1 = *(const float4*)&enc[vs][q];
        float4 r2 = *(const float4*)&enc[vd][q];
        out4[rowOff + it]          = r1;
        out4[dstOff + rowOff + it] = r2;
    }
}

extern "C" void kernel_launch(void* const* d_in, const int* in_sizes, int n_in,
                              void* d_out, int out_size, void* d_ws, size_t ws_size,
                              hipStream_t stream) {
    const int*   src = (const int*)d_in[0];
    const int*   dst = (const int*)d_in[1];
    const float* W1  = (const float*)d_in[2];
    const float* b1  = (const float*)d_in[3];
    const float* W2  = (const float*)d_in[4];
    const float* b2  = (const float*)d_in[5];

    const size_t enc_bytes = (size_t)BATCH * VOC * DIM * sizeof(float); // 6.55 MB
    if (ws_size >= enc_bytes) {
        float4* enc_ws = (float4*)d_ws;
        enc_kernel<<<BATCH, NTHREADS, 0, stream>>>(src, dst, W1, b1, W2, b2, enc_ws);
        gather_kernel<<<K2_BLOCKS, K2_THREADS, 0, stream>>>(src, dst, enc_ws, (float4*)d_out);
    } else {
        ncoe_fused_kernel<<<BATCH, NTHREADS, 0, stream>>>(src, dst, W1, b1, W2, b2, (float*)d_out);
    }
}

// Round 4
// 22.728 us; speedup vs baseline: 1.5852x; 1.5852x over previous
//
#include <hip/hip_runtime.h>

#define BATCH 256
#define SEQ   512
#define DIM   64
#define HALF  32            // output dims per block
#define VOC   100
#define NTHREADS 512
#define ENC_PITCH 36        // floats per enc row (pad: 36%4==0 for float4, breaks pow2)

typedef float f32x4 __attribute__((ext_vector_type(4)));

// grid = 512: blockIdx.x -> (row = bid>>1, half = bid&1)
__global__ __launch_bounds__(NTHREADS)
void ncoe_kernel(const int* __restrict__ src_ids,
                 const int* __restrict__ dst_ids,
                 const float* __restrict__ W1,
                 const float* __restrict__ b1,
                 const float* __restrict__ W2,
                 const float* __restrict__ b2,
                 f32x4* __restrict__ out4)
{
    __shared__ __align__(16) float sW2h[DIM][HALF];        // 8 KB  [in][out-half]
    __shared__ __align__(16) float sW1[2][DIM];            // 512 B
    __shared__ __align__(16) float sb1[DIM];               // 256 B
    __shared__ __align__(16) float sb2h[HALF];             // 128 B
    __shared__ __align__(16) float enc[VOC][ENC_PITCH];    // 14.4 KB
    __shared__ int sSrc[SEQ];                              // 2 KB
    __shared__ int sDst[SEQ];                              // 2 KB
    __shared__ int hist_s[104];
    __shared__ int hist_d[104];

    const int t    = threadIdx.x;
    const int row  = blockIdx.x >> 1;
    const int half = blockIdx.x & 1;

    // ---- stage: weights (half of W2), biases, ids; zero histograms ----
    if (t < 104) { hist_s[t] = 0; hist_d[t] = 0; }
    {
        // W2 is [64][64] row-major; take columns [half*32, half*32+32)
        const int d = t >> 3, c = t & 7;                   // 64 rows x 8 f32x4
        ((f32x4*)&sW2h[0][0])[t] =
            ((const f32x4*)W2)[d * (DIM / 4) + half * (HALF / 4) + c];
        if (t < 32)      ((f32x4*)&sW1[0][0])[t] = ((const f32x4*)W1)[t];
        else if (t < 48) ((f32x4*)sb1)[t - 32]   = ((const f32x4*)b1)[t - 32];
        else if (t < 56) ((f32x4*)sb2h)[t - 48]  = ((const f32x4*)b2)[half * (HALF / 4) + t - 48];
        sSrc[t] = src_ids[row * SEQ + t];
        sDst[t] = dst_ids[row * SEQ + t];
    }
    __syncthreads();

    // ---- per-row histograms ----
    atomicAdd(&hist_s[sSrc[t]], 1);
    atomicAdd(&hist_d[sDst[t]], 1);
    __syncthreads();

    // ---- MLP for this block's 32 output dims: 100v x 32o, 4x4 tiles -> 200 threads
    if (t < 200) {
        const int tv = t >> 3;        // 0..24
        const int to = t & 7;         // 0..7
        const int vbase = tv * 4;
        const int obase = to * 4;

        float av[4], bv[4];
        #pragma unroll
        for (int r = 0; r < 4; ++r) {
            int v = vbase + r;
            av[r] = (v == 0) ? 0.f : (float)hist_s[v];   // id 0 = padding -> zero feats
            bv[r] = (v == 0) ? 0.f : (float)hist_d[v];
        }

        float acc[4][4];
        #pragma unroll
        for (int r = 0; r < 4; ++r)
            #pragma unroll
            for (int c = 0; c < 4; ++c)
                acc[r][c] = sb2h[obase + c];

        #pragma unroll 8
        for (int d = 0; d < DIM; ++d) {
            float w10 = sW1[0][d];
            float w11 = sW1[1][d];
            float bb  = sb1[d];
            f32x4 w2 = *(const f32x4*)&sW2h[d][obase];
            #pragma unroll
            for (int r = 0; r < 4; ++r) {
                float h = fmaxf(0.f, fmaf(av[r], w10, fmaf(bv[r], w11, bb)));
                acc[r][0] = fmaf(h, w2.x, acc[r][0]);
                acc[r][1] = fmaf(h, w2.y, acc[r][1]);
                acc[r][2] = fmaf(h, w2.z, acc[r][2]);
                acc[r][3] = fmaf(h, w2.w, acc[r][3]);
            }
        }

        #pragma unroll
        for (int r = 0; r < 4; ++r) {
            f32x4 res = { acc[r][0], acc[r][1], acc[r][2], acc[r][3] };
            *(f32x4*)&enc[vbase + r][obase] = res;
        }
    }
    __syncthreads();

    // ---- gather + store this half: out[row, j, half*32 : half*32+32] ----
    const int tot = BATCH * SEQ * (DIM / 4);               // f32x4 per tensor
    #pragma unroll
    for (int k = 0; k < (SEQ * (HALF / 4)) / NTHREADS; ++k) {   // 8 iters
        int it = t + k * NTHREADS;
        int j  = it >> 3;             // 0..511
        int q  = it & 7;              // f32x4 index within the 32-dim half
        int vs = sSrc[j];
        int vd = sDst[j];
        f32x4 r1 = *(const f32x4*)&enc[vs][q * 4];
        f32x4 r2 = *(const f32x4*)&enc[vd][q * 4];
        size_t o = (((size_t)(row * SEQ + j)) << 4) + half * (HALF / 4) + q;
        __builtin_nontemporal_store(r1, &out4[o]);
        __builtin_nontemporal_store(r2, &out4[tot + o]);
    }
}

extern "C" void kernel_launch(void* const* d_in, const int* in_sizes, int n_in,
                              void* d_out, int out_size, void* d_ws, size_t ws_size,
                              hipStream_t stream) {
    const int*   src = (const int*)d_in[0];
    const int*   dst = (const int*)d_in[1];
    const float* W1  = (const float*)d_in[2];
    const float* b1  = (const float*)d_in[3];
    const float* W2  = (const float*)d_in[4];
    const float* b2  = (const float*)d_in[5];
    ncoe_kernel<<<BATCH * 2, NTHREADS, 0, stream>>>(src, dst, W1, b1, W2, b2, (f32x4*)d_out);
}

// Round 5
// 22.130 us; speedup vs baseline: 1.6281x; 1.0271x over previous
//
#include <hip/hip_runtime.h>

#define BATCH 256
#define SEQ   512
#define DIM   64
#define QRT   16            // output dims per block
#define VOC   100
#define NTHREADS 512
#define ENC_PITCH 20        // floats per enc row: 80B, 16B-aligned, 8 bank phases

typedef float f32x4 __attribute__((ext_vector_type(4)));

// grid = 1024: blockIdx.x -> (row = bid>>2, quarter = bid&3)
__global__ __launch_bounds__(NTHREADS)
void ncoe_kernel(const int* __restrict__ src_ids,
                 const int* __restrict__ dst_ids,
                 const float* __restrict__ W1,
                 const float* __restrict__ b1,
                 const float* __restrict__ W2,
                 const float* __restrict__ b2,
                 f32x4* __restrict__ out4)
{
    __shared__ __align__(16) float sW2q[DIM][QRT];         // 4 KB  [in][out-quarter]
    __shared__ __align__(16) float sW1[2][DIM];            // 512 B
    __shared__ __align__(16) float sb1[DIM];               // 256 B
    __shared__ __align__(16) float sb2q[QRT];              // 64 B
    __shared__ __align__(16) float enc[VOC][ENC_PITCH];    // 8 KB
    __shared__ int sSrc[SEQ];                              // 2 KB
    __shared__ int sDst[SEQ];                              // 2 KB
    __shared__ int hist_s[104];
    __shared__ int hist_d[104];

    const int t  = threadIdx.x;
    const int row = blockIdx.x >> 2;
    const int q4  = blockIdx.x & 3;

    // ---- stage: W2 quarter, W1, biases, ids; zero histograms ----
    if (t < 104) { hist_s[t] = 0; hist_d[t] = 0; }
    {
        if (t < 256) {
            // W2 row-major [64][64]; columns [q4*16, q4*16+16) -> 64 rows x 4 f32x4
            const int d = t >> 2, c = t & 3;
            ((f32x4*)&sW2q[0][0])[t] = ((const f32x4*)W2)[d * (DIM / 4) + q4 * 4 + c];
        } else if (t < 288) {
            ((f32x4*)&sW1[0][0])[t - 256] = ((const f32x4*)W1)[t - 256];
        } else if (t < 304) {
            ((f32x4*)sb1)[t - 288] = ((const f32x4*)b1)[t - 288];
        } else if (t < 308) {
            ((f32x4*)sb2q)[t - 304] = ((const f32x4*)b2)[q4 * 4 + (t - 304)];
        }
        sSrc[t] = src_ids[row * SEQ + t];
        sDst[t] = dst_ids[row * SEQ + t];
    }
    __syncthreads();

    // ---- per-row histograms ----
    atomicAdd(&hist_s[sSrc[t]], 1);
    atomicAdd(&hist_d[sDst[t]], 1);
    __syncthreads();

    // ---- MLP for this block's 16 output dims: 100v x 16o, 2v x 4o tiles -> 200 threads
    if (t < 200) {
        const int tv = t >> 2;        // 0..49
        const int to = t & 3;         // 0..3
        const int vbase = tv * 2;
        const int obase = to * 4;

        float av[2], bv[2];
        #pragma unroll
        for (int r = 0; r < 2; ++r) {
            int v = vbase + r;
            av[r] = (v == 0) ? 0.f : (float)hist_s[v];   // id 0 = padding -> zero feats
            bv[r] = (v == 0) ? 0.f : (float)hist_d[v];
        }

        float acc[2][4];
        #pragma unroll
        for (int r = 0; r < 2; ++r)
            #pragma unroll
            for (int c = 0; c < 4; ++c)
                acc[r][c] = sb2q[obase + c];

        #pragma unroll 8
        for (int d = 0; d < DIM; ++d) {
            float w10 = sW1[0][d];
            float w11 = sW1[1][d];
            float bb  = sb1[d];
            f32x4 w2 = *(const f32x4*)&sW2q[d][obase];
            #pragma unroll
            for (int r = 0; r < 2; ++r) {
                float h = fmaxf(0.f, fmaf(av[r], w10, fmaf(bv[r], w11, bb)));
                acc[r][0] = fmaf(h, w2.x, acc[r][0]);
                acc[r][1] = fmaf(h, w2.y, acc[r][1]);
                acc[r][2] = fmaf(h, w2.z, acc[r][2]);
                acc[r][3] = fmaf(h, w2.w, acc[r][3]);
            }
        }

        #pragma unroll
        for (int r = 0; r < 2; ++r) {
            f32x4 res = { acc[r][0], acc[r][1], acc[r][2], acc[r][3] };
            *(f32x4*)&enc[vbase + r][obase] = res;
        }
    }
    __syncthreads();

    // ---- gather + store this quarter: out[row, j, q4*16 : q4*16+16] ----
    const int tot = BATCH * SEQ * (DIM / 4);               // f32x4 per tensor
    #pragma unroll
    for (int k = 0; k < (SEQ * (QRT / 4)) / NTHREADS; ++k) {   // 4 iters
        int it = t + k * NTHREADS;
        int j  = it >> 2;             // 0..511
        int qq = it & 3;              // f32x4 index within the 16-dim quarter
        int vs = sSrc[j];
        int vd = sDst[j];
        f32x4 r1 = *(const f32x4*)&enc[vs][qq * 4];
        f32x4 r2 = *(const f32x4*)&enc[vd][qq * 4];
        size_t o = (((size_t)(row * SEQ + j)) << 4) + q4 * 4 + qq;
        out4[o]       = r1;
        out4[tot + o] = r2;
    }
}

extern "C" void kernel_launch(void* const* d_in, const int* in_sizes, int n_in,
                              void* d_out, int out_size, void* d_ws, size_t ws_size,
                              hipStream_t stream) {
    const int*   src = (const int*)d_in[0];
    const int*   dst = (const int*)d_in[1];
    const float* W1  = (const float*)d_in[2];
    const float* b1  = (const float*)d_in[3];
    const float* W2  = (const float*)d_in[4];
    const float* b2  = (const float*)d_in[5];
    ncoe_kernel<<<BATCH * 4, NTHREADS, 0, stream>>>(src, dst, W1, b1, W2, b2, (f32x4*)d_out);
}